// Round 10
// baseline (280.813 us; speedup 1.0000x reference)
//
#include <hip/hip_runtime.h>
#include <type_traits>
#include <utility>

#define B_ 4
#define T_ 160
#define S_ 80
#define F_ 640
#define H_ 1024
#define V_ 1024

typedef float f32x4 __attribute__((ext_vector_type(4)));
typedef short s16x8 __attribute__((ext_vector_type(8)));
typedef __bf16 bf16x8_t __attribute__((ext_vector_type(8)));

// ---- MFMA wrapper: hedge between V8s (short) and V8y (__bf16) builtin signatures ----
template <typename T, typename = void>
struct MfmaTakes : std::false_type {};
template <typename T>
struct MfmaTakes<T, std::void_t<decltype(__builtin_amdgcn_mfma_f32_16x16x32_bf16(
    std::declval<T>(), std::declval<T>(), std::declval<f32x4>(), 0, 0, 0))>>
    : std::true_type {};

template <typename S8>
__device__ __forceinline__ f32x4 mfma_bf16_16x16x32(S8 a, S8 b, f32x4 c) {
  if constexpr (MfmaTakes<S8>::value) {
    return __builtin_amdgcn_mfma_f32_16x16x32_bf16(a, b, c, 0, 0, 0);
  } else {
    return __builtin_amdgcn_mfma_f32_16x16x32_bf16(
        __builtin_bit_cast(bf16x8_t, a), __builtin_bit_cast(bf16x8_t, b), c, 0, 0, 0);
  }
}

// fp32 -> bf16 round-to-nearest-even (no NaN in this workload)
__device__ __forceinline__ unsigned short f2bf(float x) {
  unsigned int u = __float_as_uint(x);
  u += 0x7FFFu + ((u >> 16) & 1u);
  return (unsigned short)(u >> 16);
}

// ---------------------------------------------------------------------------
// Kernel 1: cast W1,W2 to bf16 in fragment-contiguous layout [K/8][N][8]
// so a B-fragment for mfma_16x16x32 is one 16B global load.
// ---------------------------------------------------------------------------
__global__ __launch_bounds__(256) void prep_weights(const float* __restrict__ W1,
                                                    const float* __restrict__ W2,
                                                    s16x8* __restrict__ W1p,
                                                    s16x8* __restrict__ W2p) {
  const int NW1 = (F_ / 8) * H_;   // 81920 chunks
  const int NW2 = (H_ / 8) * V_;   // 131072 chunks
  int c = blockIdx.x * 256 + threadIdx.x;
  if (c < NW1) {
    int kg = c >> 10, v = c & 1023;
    s16x8 o;
#pragma unroll
    for (int i = 0; i < 8; ++i) o[i] = (short)f2bf(W1[(kg * 8 + i) * H_ + v]);
    W1p[c] = o;
  } else if (c < NW1 + NW2) {
    int c2 = c - NW1;
    int kg = c2 >> 10, v = c2 & 1023;
    s16x8 o;
#pragma unroll
    for (int i = 0; i < 8; ++i) o[i] = (short)f2bf(W2[(kg * 8 + i) * V_ + v]);
    W2p[c2] = o;
  }
}

// ---------------------------------------------------------------------------
// Kernel 2: P = src@W1 + b1 (640 rows), Q = tgt@W1 (320 rows), fp32 out.
// 15 WGs x 512 thr; BM=64, 8 waves col-split (128 cols each); 16x16x32 MFMA.
// (~10 us; not the bottleneck — unchanged.)
// ---------------------------------------------------------------------------
__global__ __launch_bounds__(512, 2) void pq_gemm(const float* __restrict__ src,
                                                  const float* __restrict__ tgt,
                                                  const s16x8* __restrict__ W1p,
                                                  const float* __restrict__ b1,
                                                  float* __restrict__ P,
                                                  float* __restrict__ Q) {
  __shared__ s16x8 a_lds[64 * 80];  // 80 KB: rows m, 80 k-chunks, swizzled
  const int tid = threadIdx.x;
  const int wr = blockIdx.x;
  const int r0 = wr * 64;
  const bool isP = (wr < 10);  // rows 0..639 are src, 640..959 are tgt

  for (int c = tid; c < 64 * 80; c += 512) {
    int m = c / 80, kg8 = c - m * 80;
    int R = r0 + m;
    const float* rowp = isP ? (src + R * F_) : (tgt + (R - 640) * F_);
    const f32x4* p4 = (const f32x4*)(rowp + kg8 * 8);
    f32x4 x0 = p4[0], x1 = p4[1];
    s16x8 o;
#pragma unroll
    for (int i = 0; i < 4; ++i) o[i] = (short)f2bf(x0[i]);
#pragma unroll
    for (int i = 0; i < 4; ++i) o[4 + i] = (short)f2bf(x1[i]);
    a_lds[m * 80 + (kg8 ^ (m & 7))] = o;
  }
  __syncthreads();

  const int l = tid & 63, wv = tid >> 6;
  const int g = l >> 4, cl = l & 15;
  const f32x4 zero = {0.f, 0.f, 0.f, 0.f};
  f32x4 acc[4][8];
#pragma unroll
  for (int rt = 0; rt < 4; ++rt)
#pragma unroll
    for (int ct = 0; ct < 8; ++ct) acc[rt][ct] = zero;

  const s16x8* bbase = W1p + g * 1024 + wv * 128 + cl;
  s16x8 bA[8], bB[8], af[4];
#pragma unroll
  for (int ct = 0; ct < 8; ++ct) bA[ct] = bbase[ct * 16];

  for (int ks = 0; ks < 20; ks += 2) {
#pragma unroll
    for (int ct = 0; ct < 8; ++ct) bB[ct] = bbase[(ks + 1) * 4096 + ct * 16];
#pragma unroll
    for (int rt = 0; rt < 4; ++rt) {
      int m = rt * 16 + cl;
      af[rt] = a_lds[m * 80 + ((ks * 4 + g) ^ (m & 7))];
    }
#pragma unroll
    for (int ct = 0; ct < 8; ++ct)
#pragma unroll
      for (int rt = 0; rt < 4; ++rt)
        acc[rt][ct] = mfma_bf16_16x16x32(af[rt], bA[ct], acc[rt][ct]);
    int ksn = (ks + 2 < 20) ? (ks + 2) : 0;  // dummy reload on last iter
#pragma unroll
    for (int ct = 0; ct < 8; ++ct) bA[ct] = bbase[ksn * 4096 + ct * 16];
#pragma unroll
    for (int rt = 0; rt < 4; ++rt) {
      int m = rt * 16 + cl;
      af[rt] = a_lds[m * 80 + (((ks + 1) * 4 + g) ^ (m & 7))];
    }
#pragma unroll
    for (int ct = 0; ct < 8; ++ct)
#pragma unroll
      for (int rt = 0; rt < 4; ++rt)
        acc[rt][ct] = mfma_bf16_16x16x32(af[rt], bB[ct], acc[rt][ct]);
  }

  float b1v[8];
#pragma unroll
  for (int ct = 0; ct < 8; ++ct) b1v[ct] = isP ? b1[wv * 128 + ct * 16 + cl] : 0.f;
  float* outbase = isP ? P : Q;
  const int orow0 = isP ? r0 : (r0 - 640);
#pragma unroll
  for (int rt = 0; rt < 4; ++rt) {
#pragma unroll
    for (int j = 0; j < 4; ++j) {
      int row = rt * 16 + g * 4 + j;
      float* op = outbase + (size_t)(orow0 + row) * H_ + wv * 128 + cl;
#pragma unroll
      for (int ct = 0; ct < 8; ++ct) op[ct * 16] = acc[rt][ct][j] + b1v[ct];
    }
  }
}

// ---------------------------------------------------------------------------
// Kernel 3: fused h-build + GEMM2 + bias + log_softmax.
// R10 STRUCTURE: rows=64/WG to HALVE L2 B-traffic. R5-R9 analysis: MfmaUtil
// pinned at ~26% with 3.2 GB of W2p L2 reads = 18.1 TB/s observed — the
// pure-L2 BW wall (the 34.5 TB/s ubench includes L1 reuse; we have none).
// Only rows/WG cuts B bytes (softmax forces full-V WGs).
//   800 WGs x 512 thr (8 waves); wave = 64 rows x 128 cols;
//   acc[4][8] = 128 AGPR; 2 waves/SIMD -> 256 unified regs/wave, so the
//   VGPR side (~128) fits bcur[8]+bnxt[8]+af[4]+afn[4] = 96 + addr: the
//   kstep-ahead prefetch SURVIVES regalloc. Latency cover: one kstep =
//   ~1240 CU-cyc of MFMA >> ~500-cyc loaded-L2 latency.
//   LDS h = [64][129] padded (132 KB, 1 WG/CU): affine A-addressing
//   (base + imm), bank-2-way-free.
// Canary: FETCH ~55 MB / WRITE 204.8 MB exact; inflation = spill = revert.
// ---------------------------------------------------------------------------
__global__ __launch_bounds__(512, 2) void joint_main(const float* __restrict__ Pm,
                                                     const float* __restrict__ Qm,
                                                     const s16x8* __restrict__ W2p,
                                                     const float* __restrict__ b2,
                                                     float* __restrict__ out) {
  __shared__ s16x8 h_lds[64 * 129];  // 132,096 B, padded rows
  const int tid = threadIdx.x;
  int bx = blockIdx.x;
  int bid = (bx & 7) * 100 + (bx >> 3);  // XCD-contiguous swizzle (800 % 8 == 0)
  const int b = bid / 200;
  int rem = bid - b * 200;
  const int t0 = (rem / 10) * 8;
  const int s0 = (rem - (rem / 10) * 10) * 8;

  // build h = relu(P[t] + Q[s]) as bf16 into padded rows (m = 8*dt + ds)
  for (int c = tid; c < 64 * 128; c += 512) {
    int m = c >> 7, kg8 = c & 127;
    int dt = m >> 3, ds = m & 7;
    const f32x4* p4 = (const f32x4*)(Pm + (size_t)(b * T_ + t0 + dt) * H_ + kg8 * 8);
    const f32x4* q4 = (const f32x4*)(Qm + (size_t)(b * S_ + s0 + ds) * H_ + kg8 * 8);
    f32x4 x0 = p4[0] + q4[0];
    f32x4 x1 = p4[1] + q4[1];
    s16x8 o;
#pragma unroll
    for (int i = 0; i < 4; ++i) o[i] = (short)f2bf(fmaxf(x0[i], 0.f));
#pragma unroll
    for (int i = 0; i < 4; ++i) o[4 + i] = (short)f2bf(fmaxf(x1[i], 0.f));
    h_lds[m * 129 + kg8] = o;
  }
  __syncthreads();

  const int l = tid & 63, wv = tid >> 6;   // wv in 0..7, owns cols [wv*128, +128)
  const int g = l >> 4, cl = l & 15;
  f32x4 acc[4][8];
#pragma unroll
  for (int rt = 0; rt < 4; ++rt)
#pragma unroll
    for (int ct = 0; ct < 8; ++ct) acc[rt][ct] = {0.f, 0.f, 0.f, 0.f};

  // B: W2p chunk index = (ks*4+g)*1024 + wv*128 + ct*16 + cl
  const s16x8* bb = W2p + g * 1024 + wv * 128 + cl;
  // A: padded-row bases; per-kstep offset is the immediate ks*4 chunks
  const s16x8* a0p = h_lds + (0 * 16 + cl) * 129 + g;
  const s16x8* a1p = h_lds + (1 * 16 + cl) * 129 + g;
  const s16x8* a2p = h_lds + (2 * 16 + cl) * 129 + g;
  const s16x8* a3p = h_lds + (3 * 16 + cl) * 129 + g;

  s16x8 bcur[8], bnxt[8], af[4], afn[4];
#pragma unroll
  for (int i = 0; i < 8; ++i) bcur[i] = bb[i * 16];
  af[0] = a0p[0]; af[1] = a1p[0]; af[2] = a2p[0]; af[3] = a3p[0];

#pragma unroll 4
  for (int ks = 0; ks < 32; ++ks) {
    const int ksn = (ks + 1 < 32) ? ks + 1 : 0;  // dummy reload on last iter
    const s16x8* nb = bb + ksn * 4096;
#pragma unroll
    for (int i = 0; i < 8; ++i) bnxt[i] = nb[i * 16];
    afn[0] = a0p[ksn * 4]; afn[1] = a1p[ksn * 4];
    afn[2] = a2p[ksn * 4]; afn[3] = a3p[ksn * 4];
#pragma unroll
    for (int ct = 0; ct < 8; ++ct)
#pragma unroll
      for (int rt = 0; rt < 4; ++rt)
        acc[rt][ct] = mfma_bf16_16x16x32(af[rt], bcur[ct], acc[rt][ct]);
#pragma unroll
    for (int i = 0; i < 8; ++i) bcur[i] = bnxt[i];
#pragma unroll
    for (int rt = 0; rt < 4; ++rt) af[rt] = afn[rt];
  }

  // ---- epilogue: +b2, row-wise log_softmax across 8 waves, store ----
  __syncthreads();  // all waves done reading h before overlaying reductions
  float* redm = reinterpret_cast<float*>(h_lds);  // [8 waves][64 rows]
  float* reds = redm + 512;                       // [8 waves][64 rows]
  float* gmbuf = reds + 512;                      // [64 rows]
  float* lsebuf = gmbuf + 64;                     // [64 rows]

  // bias
#pragma unroll
  for (int ct = 0; ct < 8; ++ct) {
    float bv = b2[wv * 128 + ct * 16 + cl];
#pragma unroll
    for (int rt = 0; rt < 4; ++rt)
#pragma unroll
      for (int j = 0; j < 4; ++j) acc[rt][ct][j] += bv;
  }

  // per-wave per-row max -> redm (scalar chain, one row at a time)
#pragma unroll
  for (int rt = 0; rt < 4; ++rt)
#pragma unroll
    for (int j = 0; j < 4; ++j) {
      float mx = acc[rt][0][j];
#pragma unroll
      for (int ct = 1; ct < 8; ++ct) mx = fmaxf(mx, acc[rt][ct][j]);
#pragma unroll
      for (int msk = 1; msk < 16; msk <<= 1) mx = fmaxf(mx, __shfl_xor(mx, msk, 64));
      if (cl == 0) redm[wv * 64 + rt * 16 + g * 4 + j] = mx;
    }
  __syncthreads();

  // global row max (threads 0..63)
  if (tid < 64) {
    float mx = redm[tid];
#pragma unroll
    for (int w = 1; w < 8; ++w) mx = fmaxf(mx, redm[w * 64 + tid]);
    gmbuf[tid] = mx;
  }
  __syncthreads();

  // per-wave per-row partial sumexp vs global max -> reds
#pragma unroll
  for (int rt = 0; rt < 4; ++rt)
#pragma unroll
    for (int j = 0; j < 4; ++j) {
      int row = rt * 16 + g * 4 + j;
      float gm = gmbuf[row];
      float ps = 0.f;
#pragma unroll
      for (int ct = 0; ct < 8; ++ct) ps += __expf(acc[rt][ct][j] - gm);
#pragma unroll
      for (int msk = 1; msk < 16; msk <<= 1) ps += __shfl_xor(ps, msk, 64);
      if (cl == 0) reds[wv * 64 + row] = ps;
    }
  __syncthreads();

  // finalize lse per row (threads 0..63)
  if (tid < 64) {
    float s = reds[tid];
#pragma unroll
    for (int w = 1; w < 8; ++w) s += reds[w * 64 + tid];
    lsebuf[tid] = gmbuf[tid] + __logf(s);
  }
  __syncthreads();

  // store
#pragma unroll
  for (int rt = 0; rt < 4; ++rt)
#pragma unroll
    for (int j = 0; j < 4; ++j) {
      int row = rt * 16 + g * 4 + j;
      float lse = lsebuf[row];
      int n = (b * T_ + t0 + (row >> 3)) * S_ + s0 + (row & 7);
      float* op = out + (size_t)n * V_ + wv * 128 + cl;
#pragma unroll
      for (int ct = 0; ct < 8; ++ct) op[ct * 16] = acc[rt][ct][j] - lse;
    }
}

// ---------------------------------------------------------------------------
extern "C" void kernel_launch(void* const* d_in, const int* in_sizes, int n_in,
                              void* d_out, int out_size, void* d_ws, size_t ws_size,
                              hipStream_t stream) {
  const float* src = (const float*)d_in[0];  // [4,160,640]
  const float* tgt = (const float*)d_in[1];  // [4,80,640]
  const float* W1  = (const float*)d_in[2];  // [640,1024]
  const float* b1  = (const float*)d_in[3];  // [1024]
  const float* W2  = (const float*)d_in[4];  // [1024,1024]
  const float* b2  = (const float*)d_in[5];  // [1024]
  float* out = (float*)d_out;

  char* ws = (char*)d_ws;
  s16x8* W1p = (s16x8*)(ws);             // 1,310,720 B
  s16x8* W2p = (s16x8*)(ws + 1310720);   // 2,097,152 B
  float* P   = (float*)(ws + 3407872);   // 2,621,440 B  (src@W1 + b1)
  float* Q   = (float*)(ws + 6029312);   // 1,310,720 B  (tgt@W1)
  // total ws use: 7,340,032 B

  prep_weights<<<832, 256, 0, stream>>>(W1, W2, W1p, W2p);
  pq_gemm<<<15, 512, 0, stream>>>(src, tgt, W1p, b1, P, Q);
  joint_main<<<800, 512, 0, stream>>>(P, Q, W2p, b2, out);
}

// Round 11
// 254.308 us; speedup vs baseline: 1.1042x; 1.1042x over previous
//
#include <hip/hip_runtime.h>
#include <type_traits>
#include <utility>

#define B_ 4
#define T_ 160
#define S_ 80
#define F_ 640
#define H_ 1024
#define V_ 1024

typedef float f32x4 __attribute__((ext_vector_type(4)));
typedef short s16x8 __attribute__((ext_vector_type(8)));
typedef __bf16 bf16x8_t __attribute__((ext_vector_type(8)));

// ---- MFMA wrapper: hedge between V8s (short) and V8y (__bf16) builtin signatures ----
template <typename T, typename = void>
struct MfmaTakes : std::false_type {};
template <typename T>
struct MfmaTakes<T, std::void_t<decltype(__builtin_amdgcn_mfma_f32_16x16x32_bf16(
    std::declval<T>(), std::declval<T>(), std::declval<f32x4>(), 0, 0, 0))>>
    : std::true_type {};

template <typename S8>
__device__ __forceinline__ f32x4 mfma_bf16_16x16x32(S8 a, S8 b, f32x4 c) {
  if constexpr (MfmaTakes<S8>::value) {
    return __builtin_amdgcn_mfma_f32_16x16x32_bf16(a, b, c, 0, 0, 0);
  } else {
    return __builtin_amdgcn_mfma_f32_16x16x32_bf16(
        __builtin_bit_cast(bf16x8_t, a), __builtin_bit_cast(bf16x8_t, b), c, 0, 0, 0);
  }
}

// fp32 -> bf16 round-to-nearest-even (no NaN in this workload)
__device__ __forceinline__ unsigned short f2bf(float x) {
  unsigned int u = __float_as_uint(x);
  u += 0x7FFFu + ((u >> 16) & 1u);
  return (unsigned short)(u >> 16);
}

// ---------------------------------------------------------------------------
// Kernel 1: cast W1,W2 to bf16 in fragment-contiguous layout [K/8][N][8]
// so a B-fragment for mfma_16x16x32 is one 16B global load.
// ---------------------------------------------------------------------------
__global__ __launch_bounds__(256) void prep_weights(const float* __restrict__ W1,
                                                    const float* __restrict__ W2,
                                                    s16x8* __restrict__ W1p,
                                                    s16x8* __restrict__ W2p) {
  const int NW1 = (F_ / 8) * H_;   // 81920 chunks
  const int NW2 = (H_ / 8) * V_;   // 131072 chunks
  int c = blockIdx.x * 256 + threadIdx.x;
  if (c < NW1) {
    int kg = c >> 10, v = c & 1023;
    s16x8 o;
#pragma unroll
    for (int i = 0; i < 8; ++i) o[i] = (short)f2bf(W1[(kg * 8 + i) * H_ + v]);
    W1p[c] = o;
  } else if (c < NW1 + NW2) {
    int c2 = c - NW1;
    int kg = c2 >> 10, v = c2 & 1023;
    s16x8 o;
#pragma unroll
    for (int i = 0; i < 8; ++i) o[i] = (short)f2bf(W2[(kg * 8 + i) * V_ + v]);
    W2p[c2] = o;
  }
}

// ---------------------------------------------------------------------------
// Kernel 2: P = src@W1 + b1 (640 rows), Q = tgt@W1 (320 rows), fp32 out.
// 15 WGs x 512 thr; BM=64, 8 waves col-split (128 cols each); 16x16x32 MFMA.
// (~10 us; not the bottleneck — unchanged.)
// ---------------------------------------------------------------------------
__global__ __launch_bounds__(512, 2) void pq_gemm(const float* __restrict__ src,
                                                  const float* __restrict__ tgt,
                                                  const s16x8* __restrict__ W1p,
                                                  const float* __restrict__ b1,
                                                  float* __restrict__ P,
                                                  float* __restrict__ Q) {
  __shared__ s16x8 a_lds[64 * 80];  // 80 KB: rows m, 80 k-chunks, swizzled
  const int tid = threadIdx.x;
  const int wr = blockIdx.x;
  const int r0 = wr * 64;
  const bool isP = (wr < 10);  // rows 0..639 are src, 640..959 are tgt

  for (int c = tid; c < 64 * 80; c += 512) {
    int m = c / 80, kg8 = c - m * 80;
    int R = r0 + m;
    const float* rowp = isP ? (src + R * F_) : (tgt + (R - 640) * F_);
    const f32x4* p4 = (const f32x4*)(rowp + kg8 * 8);
    f32x4 x0 = p4[0], x1 = p4[1];
    s16x8 o;
#pragma unroll
    for (int i = 0; i < 4; ++i) o[i] = (short)f2bf(x0[i]);
#pragma unroll
    for (int i = 0; i < 4; ++i) o[4 + i] = (short)f2bf(x1[i]);
    a_lds[m * 80 + (kg8 ^ (m & 7))] = o;
  }
  __syncthreads();

  const int l = tid & 63, wv = tid >> 6;
  const int g = l >> 4, cl = l & 15;
  const f32x4 zero = {0.f, 0.f, 0.f, 0.f};
  f32x4 acc[4][8];
#pragma unroll
  for (int rt = 0; rt < 4; ++rt)
#pragma unroll
    for (int ct = 0; ct < 8; ++ct) acc[rt][ct] = zero;

  const s16x8* bbase = W1p + g * 1024 + wv * 128 + cl;
  s16x8 bA[8], bB[8], af[4];
#pragma unroll
  for (int ct = 0; ct < 8; ++ct) bA[ct] = bbase[ct * 16];

  for (int ks = 0; ks < 20; ks += 2) {
#pragma unroll
    for (int ct = 0; ct < 8; ++ct) bB[ct] = bbase[(ks + 1) * 4096 + ct * 16];
#pragma unroll
    for (int rt = 0; rt < 4; ++rt) {
      int m = rt * 16 + cl;
      af[rt] = a_lds[m * 80 + ((ks * 4 + g) ^ (m & 7))];
    }
#pragma unroll
    for (int ct = 0; ct < 8; ++ct)
#pragma unroll
      for (int rt = 0; rt < 4; ++rt)
        acc[rt][ct] = mfma_bf16_16x16x32(af[rt], bA[ct], acc[rt][ct]);
    int ksn = (ks + 2 < 20) ? (ks + 2) : 0;  // dummy reload on last iter
#pragma unroll
    for (int ct = 0; ct < 8; ++ct) bA[ct] = bbase[ksn * 4096 + ct * 16];
#pragma unroll
    for (int rt = 0; rt < 4; ++rt) {
      int m = rt * 16 + cl;
      af[rt] = a_lds[m * 80 + (((ks + 1) * 4 + g) ^ (m & 7))];
    }
#pragma unroll
    for (int ct = 0; ct < 8; ++ct)
#pragma unroll
      for (int rt = 0; rt < 4; ++rt)
        acc[rt][ct] = mfma_bf16_16x16x32(af[rt], bB[ct], acc[rt][ct]);
  }

  float b1v[8];
#pragma unroll
  for (int ct = 0; ct < 8; ++ct) b1v[ct] = isP ? b1[wv * 128 + ct * 16 + cl] : 0.f;
  float* outbase = isP ? P : Q;
  const int orow0 = isP ? r0 : (r0 - 640);
#pragma unroll
  for (int rt = 0; rt < 4; ++rt) {
#pragma unroll
    for (int j = 0; j < 4; ++j) {
      int row = rt * 16 + g * 4 + j;
      float* op = outbase + (size_t)(orow0 + row) * H_ + wv * 128 + cl;
#pragma unroll
      for (int ct = 0; ct < 8; ++ct) op[ct * 16] = acc[rt][ct][j] + b1v[ct];
    }
  }
}

// ---------------------------------------------------------------------------
// Kernel 3: fused h-build + GEMM2 + bias + log_softmax.
// R11 STRUCTURE: MAX OCCUPANCY. R5-R10 showed MfmaUtil tracks waves/SIMD
// (2->16.7%, 4->22.5/26.7%) and nothing else moves it: the K-loop is
// load-use latency-bound; cover scales with TLP. This config hits the HW
// max 8 waves/SIMD: 1600 WGs x 1024 thr (16 waves); tile 32 rows x 1024
// cols; wave owns 64 cols; h_lds 66 KB -> 2 WGs/CU -> 32 waves/CU.
// __launch_bounds__(1024,8) forces the 64-reg/wave cap: acc[2][4]=32 AGPR
// + b[4]=16 + a[2]=8 + addr ~6 = ~62. K-loop single-buffered (no manual
// prefetch): a stalling wave is covered by 7 siblings (7x155 cyc MFMA >
// ~700 cyc loaded-L2 latency).
// Canary: FETCH ~59 MB / WRITE 204.8 MB exact; inflation = spill = revert.
// ---------------------------------------------------------------------------
__global__ __launch_bounds__(1024, 8) void joint_main(const float* __restrict__ Pm,
                                                      const float* __restrict__ Qm,
                                                      const s16x8* __restrict__ W2p,
                                                      const float* __restrict__ b2,
                                                      float* __restrict__ out) {
  __shared__ s16x8 h_lds[32 * 129];  // 66048 B, padded rows -> 2 WGs/CU
  const int tid = threadIdx.x;
  int bx = blockIdx.x;
  int bid = (bx & 7) * 200 + (bx >> 3);  // XCD-contiguous swizzle (1600 % 8 == 0)
  const int b = bid / 400;
  int rem = bid - b * 400;
  const int t0 = (rem / 10) * 4;
  const int s0 = (rem - (rem / 10) * 10) * 8;

  // build h = relu(P[t] + Q[s]) as bf16 into padded rows (m = 8*dt + ds)
  for (int c = tid; c < 32 * 128; c += 1024) {
    int m = c >> 7, kg8 = c & 127;
    int dt = m >> 3, ds = m & 7;
    const f32x4* p4 = (const f32x4*)(Pm + (size_t)(b * T_ + t0 + dt) * H_ + kg8 * 8);
    const f32x4* q4 = (const f32x4*)(Qm + (size_t)(b * S_ + s0 + ds) * H_ + kg8 * 8);
    f32x4 x0 = p4[0] + q4[0];
    f32x4 x1 = p4[1] + q4[1];
    s16x8 o;
#pragma unroll
    for (int i = 0; i < 4; ++i) o[i] = (short)f2bf(fmaxf(x0[i], 0.f));
#pragma unroll
    for (int i = 0; i < 4; ++i) o[4 + i] = (short)f2bf(fmaxf(x1[i], 0.f));
    h_lds[m * 129 + kg8] = o;
  }
  __syncthreads();

  const int l = tid & 63, wv = tid >> 6;   // wv in 0..15, owns cols [wv*64, +64)
  const int g = l >> 4, cl = l & 15;
  f32x4 acc[2][4];
#pragma unroll
  for (int rt = 0; rt < 2; ++rt)
#pragma unroll
    for (int ct = 0; ct < 4; ++ct) acc[rt][ct] = {0.f, 0.f, 0.f, 0.f};

  // B: W2p chunk index = (ks*4+g)*1024 + wv*64 + ct*16 + cl
  const s16x8* bb = W2p + g * 1024 + wv * 64 + cl;
  // A: padded-row bases; per-kstep offset = ks*4 chunks (64 B)
  const s16x8* a0p = h_lds + cl * 129 + g;
  const s16x8* a1p = h_lds + (16 + cl) * 129 + g;

  // single-buffered K-loop: load-then-use; 8 waves/SIMD provide the cover
#pragma unroll 2
  for (int ks = 0; ks < 32; ++ks) {
    const s16x8* base = bb + ks * 4096;
    s16x8 bf0 = base[0];
    s16x8 bf1 = base[16];
    s16x8 bf2 = base[32];
    s16x8 bf3 = base[48];
    s16x8 a0 = a0p[ks * 4];
    s16x8 a1 = a1p[ks * 4];
    acc[0][0] = mfma_bf16_16x16x32(a0, bf0, acc[0][0]);
    acc[1][0] = mfma_bf16_16x16x32(a1, bf0, acc[1][0]);
    acc[0][1] = mfma_bf16_16x16x32(a0, bf1, acc[0][1]);
    acc[1][1] = mfma_bf16_16x16x32(a1, bf1, acc[1][1]);
    acc[0][2] = mfma_bf16_16x16x32(a0, bf2, acc[0][2]);
    acc[1][2] = mfma_bf16_16x16x32(a1, bf2, acc[1][2]);
    acc[0][3] = mfma_bf16_16x16x32(a0, bf3, acc[0][3]);
    acc[1][3] = mfma_bf16_16x16x32(a1, bf3, acc[1][3]);
  }

  // ---- epilogue: +b2, row-wise log_softmax across 16 waves, store ----
  __syncthreads();  // all waves done reading h before overlaying reductions
  float* redm = reinterpret_cast<float*>(h_lds);  // [16 waves][32 rows]
  float* reds = redm + 512;                       // [16 waves][32 rows]
  float* gmbuf = reds + 512;                      // [32 rows]
  float* lsebuf = gmbuf + 32;                     // [32 rows]

  // bias
#pragma unroll
  for (int ct = 0; ct < 4; ++ct) {
    float bv = b2[wv * 64 + ct * 16 + cl];
#pragma unroll
    for (int rt = 0; rt < 2; ++rt)
#pragma unroll
      for (int j = 0; j < 4; ++j) acc[rt][ct][j] += bv;
  }

  // per-wave per-row max -> redm (scalar chain, one row at a time)
#pragma unroll
  for (int rt = 0; rt < 2; ++rt)
#pragma unroll
    for (int j = 0; j < 4; ++j) {
      float mx = fmaxf(fmaxf(acc[rt][0][j], acc[rt][1][j]),
                       fmaxf(acc[rt][2][j], acc[rt][3][j]));
#pragma unroll
      for (int msk = 1; msk < 16; msk <<= 1) mx = fmaxf(mx, __shfl_xor(mx, msk, 64));
      if (cl == 0) redm[wv * 32 + rt * 16 + g * 4 + j] = mx;
    }
  __syncthreads();

  // global row max (threads 0..31)
  if (tid < 32) {
    float mx = redm[tid];
#pragma unroll
    for (int w = 1; w < 16; ++w) mx = fmaxf(mx, redm[w * 32 + tid]);
    gmbuf[tid] = mx;
  }
  __syncthreads();

  // per-wave per-row partial sumexp vs global max -> reds
#pragma unroll
  for (int rt = 0; rt < 2; ++rt)
#pragma unroll
    for (int j = 0; j < 4; ++j) {
      int row = rt * 16 + g * 4 + j;
      float gm = gmbuf[row];
      float ps = __expf(acc[rt][0][j] - gm) + __expf(acc[rt][1][j] - gm) +
                 __expf(acc[rt][2][j] - gm) + __expf(acc[rt][3][j] - gm);
#pragma unroll
      for (int msk = 1; msk < 16; msk <<= 1) ps += __shfl_xor(ps, msk, 64);
      if (cl == 0) reds[wv * 32 + row] = ps;
    }
  __syncthreads();

  // finalize lse per row (threads 0..31)
  if (tid < 32) {
    float s = reds[tid];
#pragma unroll
    for (int w = 1; w < 16; ++w) s += reds[w * 32 + tid];
    lsebuf[tid] = gmbuf[tid] + __logf(s);
  }
  __syncthreads();

  // store
#pragma unroll
  for (int rt = 0; rt < 2; ++rt)
#pragma unroll
    for (int j = 0; j < 4; ++j) {
      int row = rt * 16 + g * 4 + j;
      float lse = lsebuf[row];
      int n = (b * T_ + t0 + (row >> 3)) * S_ + s0 + (row & 7);
      float* op = out + (size_t)n * V_ + wv * 64 + cl;
#pragma unroll
      for (int ct = 0; ct < 4; ++ct) op[ct * 16] = acc[rt][ct][j] - lse;
    }
}

// ---------------------------------------------------------------------------
extern "C" void kernel_launch(void* const* d_in, const int* in_sizes, int n_in,
                              void* d_out, int out_size, void* d_ws, size_t ws_size,
                              hipStream_t stream) {
  const float* src = (const float*)d_in[0];  // [4,160,640]
  const float* tgt = (const float*)d_in[1];  // [4,80,640]
  const float* W1  = (const float*)d_in[2];  // [640,1024]
  const float* b1  = (const float*)d_in[3];  // [1024]
  const float* W2  = (const float*)d_in[4];  // [1024,1024]
  const float* b2  = (const float*)d_in[5];  // [1024]
  float* out = (float*)d_out;

  char* ws = (char*)d_ws;
  s16x8* W1p = (s16x8*)(ws);             // 1,310,720 B
  s16x8* W2p = (s16x8*)(ws + 1310720);   // 2,097,152 B
  float* P   = (float*)(ws + 3407872);   // 2,621,440 B  (src@W1 + b1)
  float* Q   = (float*)(ws + 6029312);   // 1,310,720 B  (tgt@W1)
  // total ws use: 7,340,032 B

  prep_weights<<<832, 256, 0, stream>>>(W1, W2, W1p, W2p);
  pq_gemm<<<15, 512, 0, stream>>>(src, tgt, W1p, b1, P, Q);
  joint_main<<<1600, 1024, 0, stream>>>(P, Q, W2p, b2, out);
}

// Round 12
// 209.312 us; speedup vs baseline: 1.3416x; 1.2150x over previous
//
#include <hip/hip_runtime.h>
#include <type_traits>
#include <utility>

#define B_ 4
#define T_ 160
#define S_ 80
#define F_ 640
#define H_ 1024
#define V_ 1024

typedef float f32x4 __attribute__((ext_vector_type(4)));
typedef short s16x8 __attribute__((ext_vector_type(8)));
typedef __bf16 bf16x8_t __attribute__((ext_vector_type(8)));

// ---- MFMA wrapper: hedge between V8s (short) and V8y (__bf16) builtin signatures ----
template <typename T, typename = void>
struct MfmaTakes : std::false_type {};
template <typename T>
struct MfmaTakes<T, std::void_t<decltype(__builtin_amdgcn_mfma_f32_16x16x32_bf16(
    std::declval<T>(), std::declval<T>(), std::declval<f32x4>(), 0, 0, 0))>>
    : std::true_type {};

template <typename S8>
__device__ __forceinline__ f32x4 mfma_bf16_16x16x32(S8 a, S8 b, f32x4 c) {
  if constexpr (MfmaTakes<S8>::value) {
    return __builtin_amdgcn_mfma_f32_16x16x32_bf16(a, b, c, 0, 0, 0);
  } else {
    return __builtin_amdgcn_mfma_f32_16x16x32_bf16(
        __builtin_bit_cast(bf16x8_t, a), __builtin_bit_cast(bf16x8_t, b), c, 0, 0, 0);
  }
}

// fp32 -> bf16 round-to-nearest-even (no NaN in this workload)
__device__ __forceinline__ unsigned short f2bf(float x) {
  unsigned int u = __float_as_uint(x);
  u += 0x7FFFu + ((u >> 16) & 1u);
  return (unsigned short)(u >> 16);
}

// ---------------------------------------------------------------------------
// Kernel 1: cast W1,W2 to bf16 in fragment-contiguous layout [K/8][N][8]
// so a B-fragment for mfma_16x16x32 is one 16B global load.
// ---------------------------------------------------------------------------
__global__ __launch_bounds__(256) void prep_weights(const float* __restrict__ W1,
                                                    const float* __restrict__ W2,
                                                    s16x8* __restrict__ W1p,
                                                    s16x8* __restrict__ W2p) {
  const int NW1 = (F_ / 8) * H_;   // 81920 chunks
  const int NW2 = (H_ / 8) * V_;   // 131072 chunks
  int c = blockIdx.x * 256 + threadIdx.x;
  if (c < NW1) {
    int kg = c >> 10, v = c & 1023;
    s16x8 o;
#pragma unroll
    for (int i = 0; i < 8; ++i) o[i] = (short)f2bf(W1[(kg * 8 + i) * H_ + v]);
    W1p[c] = o;
  } else if (c < NW1 + NW2) {
    int c2 = c - NW1;
    int kg = c2 >> 10, v = c2 & 1023;
    s16x8 o;
#pragma unroll
    for (int i = 0; i < 8; ++i) o[i] = (short)f2bf(W2[(kg * 8 + i) * V_ + v]);
    W2p[c2] = o;
  }
}

// ---------------------------------------------------------------------------
// Kernel 2: P = src@W1 + b1 (640 rows), Q = tgt@W1 (320 rows), fp32 out.
// 15 WGs x 512 thr; BM=64, 8 waves col-split (128 cols each); 16x16x32 MFMA.
// (~10 us; not the bottleneck — unchanged.)
// ---------------------------------------------------------------------------
__global__ __launch_bounds__(512, 2) void pq_gemm(const float* __restrict__ src,
                                                  const float* __restrict__ tgt,
                                                  const s16x8* __restrict__ W1p,
                                                  const float* __restrict__ b1,
                                                  float* __restrict__ P,
                                                  float* __restrict__ Q) {
  __shared__ s16x8 a_lds[64 * 80];  // 80 KB: rows m, 80 k-chunks, swizzled
  const int tid = threadIdx.x;
  const int wr = blockIdx.x;
  const int r0 = wr * 64;
  const bool isP = (wr < 10);  // rows 0..639 are src, 640..959 are tgt

  for (int c = tid; c < 64 * 80; c += 512) {
    int m = c / 80, kg8 = c - m * 80;
    int R = r0 + m;
    const float* rowp = isP ? (src + R * F_) : (tgt + (R - 640) * F_);
    const f32x4* p4 = (const f32x4*)(rowp + kg8 * 8);
    f32x4 x0 = p4[0], x1 = p4[1];
    s16x8 o;
#pragma unroll
    for (int i = 0; i < 4; ++i) o[i] = (short)f2bf(x0[i]);
#pragma unroll
    for (int i = 0; i < 4; ++i) o[4 + i] = (short)f2bf(x1[i]);
    a_lds[m * 80 + (kg8 ^ (m & 7))] = o;
  }
  __syncthreads();

  const int l = tid & 63, wv = tid >> 6;
  const int g = l >> 4, cl = l & 15;
  const f32x4 zero = {0.f, 0.f, 0.f, 0.f};
  f32x4 acc[4][8];
#pragma unroll
  for (int rt = 0; rt < 4; ++rt)
#pragma unroll
    for (int ct = 0; ct < 8; ++ct) acc[rt][ct] = zero;

  const s16x8* bbase = W1p + g * 1024 + wv * 128 + cl;
  s16x8 bA[8], bB[8], af[4];
#pragma unroll
  for (int ct = 0; ct < 8; ++ct) bA[ct] = bbase[ct * 16];

  for (int ks = 0; ks < 20; ks += 2) {
#pragma unroll
    for (int ct = 0; ct < 8; ++ct) bB[ct] = bbase[(ks + 1) * 4096 + ct * 16];
#pragma unroll
    for (int rt = 0; rt < 4; ++rt) {
      int m = rt * 16 + cl;
      af[rt] = a_lds[m * 80 + ((ks * 4 + g) ^ (m & 7))];
    }
#pragma unroll
    for (int ct = 0; ct < 8; ++ct)
#pragma unroll
      for (int rt = 0; rt < 4; ++rt)
        acc[rt][ct] = mfma_bf16_16x16x32(af[rt], bA[ct], acc[rt][ct]);
    int ksn = (ks + 2 < 20) ? (ks + 2) : 0;  // dummy reload on last iter
#pragma unroll
    for (int ct = 0; ct < 8; ++ct) bA[ct] = bbase[ksn * 4096 + ct * 16];
#pragma unroll
    for (int rt = 0; rt < 4; ++rt) {
      int m = rt * 16 + cl;
      af[rt] = a_lds[m * 80 + (((ks + 1) * 4 + g) ^ (m & 7))];
    }
#pragma unroll
    for (int ct = 0; ct < 8; ++ct)
#pragma unroll
      for (int rt = 0; rt < 4; ++rt)
        acc[rt][ct] = mfma_bf16_16x16x32(af[rt], bB[ct], acc[rt][ct]);
  }

  float b1v[8];
#pragma unroll
  for (int ct = 0; ct < 8; ++ct) b1v[ct] = isP ? b1[wv * 128 + ct * 16 + cl] : 0.f;
  float* outbase = isP ? P : Q;
  const int orow0 = isP ? r0 : (r0 - 640);
#pragma unroll
  for (int rt = 0; rt < 4; ++rt) {
#pragma unroll
    for (int j = 0; j < 4; ++j) {
      int row = rt * 16 + g * 4 + j;
      float* op = outbase + (size_t)(orow0 + row) * H_ + wv * 128 + cl;
#pragma unroll
      for (int ct = 0; ct < 8; ++ct) op[ct * 16] = acc[rt][ct][j] + b1v[ct];
    }
  }
}

// ---------------------------------------------------------------------------
// Kernel 3: fused h-build + GEMM2 + bias + log_softmax.
// R12: CUT L2 TRAFFIC (the real wall). Cross-round: R7/R9 stream W2p at
// ~18 TB/s (pure-L2, no L1 reuse) and sit exactly at the 3.2GB/18TB/s =
// ~180us floor; occupancy/latency/VALU knobs all null (R6/R8/R11).
// B-bytes = 2MB x #WGs, so rows=64/WG halves traffic -> 1.6GB, floor ~89us.
//   800 WGs x 1024 thr (16 waves, 4/SIMD, 1 WG/CU). Wave = 64 rows x 64
//   cols: acc[4][4] = 64 AGPR; VGPR side at the 128-reg cap: b[4]=16 +
//   a[4]=16 + addr ~10 fits single-buffered (R5's failure was XOR-VALU
//   addressing + spilling epilogue, both fixed since: affine padded LDS
//   [64][129] (base+imm, zero VALU per A-read) + scalar LDS epilogue).
// Canary: FETCH ~39 MB / WRITE 204.8 MB exact; inflation = spill = revert.
// ---------------------------------------------------------------------------
__global__ __launch_bounds__(1024, 4) void joint_main(const float* __restrict__ Pm,
                                                      const float* __restrict__ Qm,
                                                      const s16x8* __restrict__ W2p,
                                                      const float* __restrict__ b2,
                                                      float* __restrict__ out) {
  __shared__ s16x8 h_lds[64 * 129];  // 132,096 B, padded rows -> 1 WG/CU
  const int tid = threadIdx.x;
  int bx = blockIdx.x;
  int bid = (bx & 7) * 100 + (bx >> 3);  // XCD-contiguous swizzle (800 % 8 == 0)
  const int b = bid / 200;
  int rem = bid - b * 200;
  const int t0 = (rem / 10) * 8;
  const int s0 = (rem - (rem / 10) * 10) * 8;

  // build h = relu(P[t] + Q[s]) as bf16 into padded rows (m = 8*dt + ds)
  for (int c = tid; c < 64 * 128; c += 1024) {
    int m = c >> 7, kg8 = c & 127;
    int dt = m >> 3, ds = m & 7;
    const f32x4* p4 = (const f32x4*)(Pm + (size_t)(b * T_ + t0 + dt) * H_ + kg8 * 8);
    const f32x4* q4 = (const f32x4*)(Qm + (size_t)(b * S_ + s0 + ds) * H_ + kg8 * 8);
    f32x4 x0 = p4[0] + q4[0];
    f32x4 x1 = p4[1] + q4[1];
    s16x8 o;
#pragma unroll
    for (int i = 0; i < 4; ++i) o[i] = (short)f2bf(fmaxf(x0[i], 0.f));
#pragma unroll
    for (int i = 0; i < 4; ++i) o[4 + i] = (short)f2bf(fmaxf(x1[i], 0.f));
    h_lds[m * 129 + kg8] = o;
  }
  __syncthreads();

  const int l = tid & 63, wv = tid >> 6;   // wv in 0..15, owns cols [wv*64, +64)
  const int g = l >> 4, cl = l & 15;
  f32x4 acc[4][4];
#pragma unroll
  for (int rt = 0; rt < 4; ++rt)
#pragma unroll
    for (int ct = 0; ct < 4; ++ct) acc[rt][ct] = {0.f, 0.f, 0.f, 0.f};

  // B: W2p chunk index = (ks*4+g)*1024 + wv*64 + ct*16 + cl
  const s16x8* bb = W2p + g * 1024 + wv * 64 + cl;
  // A: padded-row bases; per-kstep offset = ks*4 chunks (pure immediates)
  const s16x8* a0p = h_lds + (0 * 16 + cl) * 129 + g;
  const s16x8* a1p = h_lds + (1 * 16 + cl) * 129 + g;
  const s16x8* a2p = h_lds + (2 * 16 + cl) * 129 + g;
  const s16x8* a3p = h_lds + (3 * 16 + cl) * 129 + g;

  // single-buffered K-loop; affine addressing; compiler pipelines within cap
#pragma unroll 4
  for (int ks = 0; ks < 32; ++ks) {
    const s16x8* base = bb + ks * 4096;
    s16x8 bf0 = base[0];
    s16x8 bf1 = base[16];
    s16x8 bf2 = base[32];
    s16x8 bf3 = base[48];
    s16x8 a0 = a0p[ks * 4];
    s16x8 a1 = a1p[ks * 4];
    s16x8 a2 = a2p[ks * 4];
    s16x8 a3 = a3p[ks * 4];
    acc[0][0] = mfma_bf16_16x16x32(a0, bf0, acc[0][0]);
    acc[1][0] = mfma_bf16_16x16x32(a1, bf0, acc[1][0]);
    acc[2][0] = mfma_bf16_16x16x32(a2, bf0, acc[2][0]);
    acc[3][0] = mfma_bf16_16x16x32(a3, bf0, acc[3][0]);
    acc[0][1] = mfma_bf16_16x16x32(a0, bf1, acc[0][1]);
    acc[1][1] = mfma_bf16_16x16x32(a1, bf1, acc[1][1]);
    acc[2][1] = mfma_bf16_16x16x32(a2, bf1, acc[2][1]);
    acc[3][1] = mfma_bf16_16x16x32(a3, bf1, acc[3][1]);
    acc[0][2] = mfma_bf16_16x16x32(a0, bf2, acc[0][2]);
    acc[1][2] = mfma_bf16_16x16x32(a1, bf2, acc[1][2]);
    acc[2][2] = mfma_bf16_16x16x32(a2, bf2, acc[2][2]);
    acc[3][2] = mfma_bf16_16x16x32(a3, bf2, acc[3][2]);
    acc[0][3] = mfma_bf16_16x16x32(a0, bf3, acc[0][3]);
    acc[1][3] = mfma_bf16_16x16x32(a1, bf3, acc[1][3]);
    acc[2][3] = mfma_bf16_16x16x32(a2, bf3, acc[2][3]);
    acc[3][3] = mfma_bf16_16x16x32(a3, bf3, acc[3][3]);
  }

  // ---- epilogue: +b2, row-wise log_softmax across 16 waves, store ----
  __syncthreads();  // all waves done reading h before overlaying reductions
  float* redm = reinterpret_cast<float*>(h_lds);  // [16 waves][64 rows]
  float* reds = redm + 1024;                      // [16 waves][64 rows]
  float* gmbuf = reds + 1024;                     // [64 rows]
  float* lsebuf = gmbuf + 64;                     // [64 rows]

  // bias
#pragma unroll
  for (int ct = 0; ct < 4; ++ct) {
    float bv = b2[wv * 64 + ct * 16 + cl];
#pragma unroll
    for (int rt = 0; rt < 4; ++rt)
#pragma unroll
      for (int j = 0; j < 4; ++j) acc[rt][ct][j] += bv;
  }

  // per-wave per-row max -> redm (scalar chain, one row at a time)
#pragma unroll
  for (int rt = 0; rt < 4; ++rt)
#pragma unroll
    for (int j = 0; j < 4; ++j) {
      float mx = fmaxf(fmaxf(acc[rt][0][j], acc[rt][1][j]),
                       fmaxf(acc[rt][2][j], acc[rt][3][j]));
#pragma unroll
      for (int msk = 1; msk < 16; msk <<= 1) mx = fmaxf(mx, __shfl_xor(mx, msk, 64));
      if (cl == 0) redm[wv * 64 + rt * 16 + g * 4 + j] = mx;
    }
  __syncthreads();

  // global row max (threads 0..63)
  if (tid < 64) {
    float mx = redm[tid];
#pragma unroll
    for (int w = 1; w < 16; ++w) mx = fmaxf(mx, redm[w * 64 + tid]);
    gmbuf[tid] = mx;
  }
  __syncthreads();

  // per-wave per-row partial sumexp vs global max -> reds
#pragma unroll
  for (int rt = 0; rt < 4; ++rt)
#pragma unroll
    for (int j = 0; j < 4; ++j) {
      int row = rt * 16 + g * 4 + j;
      float gm = gmbuf[row];
      float ps = __expf(acc[rt][0][j] - gm) + __expf(acc[rt][1][j] - gm) +
                 __expf(acc[rt][2][j] - gm) + __expf(acc[rt][3][j] - gm);
#pragma unroll
      for (int msk = 1; msk < 16; msk <<= 1) ps += __shfl_xor(ps, msk, 64);
      if (cl == 0) reds[wv * 64 + row] = ps;
    }
  __syncthreads();

  // finalize lse per row (threads 0..63)
  if (tid < 64) {
    float s = reds[tid];
#pragma unroll
    for (int w = 1; w < 16; ++w) s += reds[w * 64 + tid];
    lsebuf[tid] = gmbuf[tid] + __logf(s);
  }
  __syncthreads();

  // store
#pragma unroll
  for (int rt = 0; rt < 4; ++rt)
#pragma unroll
    for (int j = 0; j < 4; ++j) {
      int row = rt * 16 + g * 4 + j;
      float lse = lsebuf[row];
      int n = (b * T_ + t0 + (row >> 3)) * S_ + s0 + (row & 7);
      float* op = out + (size_t)n * V_ + wv * 64 + cl;
#pragma unroll
      for (int ct = 0; ct < 4; ++ct) op[ct * 16] = acc[rt][ct][j] - lse;
    }
}

// ---------------------------------------------------------------------------
extern "C" void kernel_launch(void* const* d_in, const int* in_sizes, int n_in,
                              void* d_out, int out_size, void* d_ws, size_t ws_size,
                              hipStream_t stream) {
  const float* src = (const float*)d_in[0];  // [4,160,640]
  const float* tgt = (const float*)d_in[1];  // [4,80,640]
  const float* W1  = (const float*)d_in[2];  // [640,1024]
  const float* b1  = (const float*)d_in[3];  // [1024]
  const float* W2  = (const float*)d_in[4];  // [1024,1024]
  const float* b2  = (const float*)d_in[5];  // [1024]
  float* out = (float*)d_out;

  char* ws = (char*)d_ws;
  s16x8* W1p = (s16x8*)(ws);             // 1,310,720 B
  s16x8* W2p = (s16x8*)(ws + 1310720);   // 2,097,152 B
  float* P   = (float*)(ws + 3407872);   // 2,621,440 B  (src@W1 + b1)
  float* Q   = (float*)(ws + 6029312);   // 1,310,720 B  (tgt@W1)
  // total ws use: 7,340,032 B

  prep_weights<<<832, 256, 0, stream>>>(W1, W2, W1p, W2p);
  pq_gemm<<<15, 512, 0, stream>>>(src, tgt, W1p, b1, P, Q);
  joint_main<<<800, 1024, 0, stream>>>(P, Q, W2p, b2, out);
}